// Round 15
// baseline (5773.607 us; speedup 1.0000x reference)
//
#include <hip/hip_runtime.h>
#include <hip/hip_bf16.h>

// ---------------------------------------------------------------------------
// conv1d embed -> LSTM encoder (512 steps, B=64, H=512) -> decoder (decoupled
// h-recurrence + batched attention) -> projection.
// r15: encoder split in two phases. Phase A = lstm steps 0-127 (64 blocks)
// + 3072 fused GEMM blocks staging xw for steps 128-511 on the idle 192 CUs.
// Phase B = lstm steps 128-511 (stream-ordered after fused GEMM: no race).
// Hides ~85 us of staging GEMM under the recurrence.
// ---------------------------------------------------------------------------

typedef short bf16x8 __attribute__((ext_vector_type(8)));
typedef float f32x4 __attribute__((ext_vector_type(4)));

static __device__ __forceinline__ float bf2f(unsigned short u){
  return __uint_as_float(((unsigned)u) << 16);
}
static __device__ __forceinline__ unsigned short f2bf(float f){
  unsigned x = __float_as_uint(f);
  return (unsigned short)((x + 0x7fffu + ((x >> 16) & 1u)) >> 16);   // RNE
}
static __device__ __forceinline__ float sigm(float x){
  return __builtin_amdgcn_rcpf(1.f + __builtin_amdgcn_exp2f(-1.44269504f*x));
}
static __device__ __forceinline__ float tanh2(float x){
  return 1.f - 2.f*__builtin_amdgcn_rcpf(1.f + __builtin_amdgcn_exp2f(2.88539008f*x));
}

static __device__ __forceinline__ unsigned ldu(const unsigned* p){
  return __hip_atomic_load(p, __ATOMIC_RELAXED, __HIP_MEMORY_SCOPE_AGENT);
}
static __device__ __forceinline__ void stu(unsigned* p, unsigned v){
  __hip_atomic_store(p, v, __ATOMIC_RELAXED, __HIP_MEMORY_SCOPE_AGENT);
}
static __device__ __forceinline__ unsigned long long ldq(const unsigned long long* p){
  return __hip_atomic_load(p, __ATOMIC_RELAXED, __HIP_MEMORY_SCOPE_AGENT);
}
static __device__ __forceinline__ void stq(unsigned long long* p, unsigned long long v){
  __hip_atomic_store(p, v, __ATOMIC_RELAXED, __HIP_MEMORY_SCOPE_AGENT);
}
#define VMWAIT() __asm__ __volatile__("s_waitcnt vmcnt(0)" ::: "memory")

// ----------------------------- small utility kernels -----------------------

__global__ void cast_k(const float* __restrict__ src, unsigned short* __restrict__ dst, int n){
  int i = blockIdx.x*256 + threadIdx.x;
  if (i < n) dst[i] = f2bf(src[i]);
}

__global__ void split_attn_k(const float* __restrict__ aw,
                             unsigned short* __restrict__ wh, unsigned short* __restrict__ we){
  int i = blockIdx.x*256 + threadIdx.x;
  int nrow = i >> 9, k = i & 511;
  wh[i] = f2bf(aw[(size_t)nrow*1024 + k]);
  we[i] = f2bf(aw[(size_t)nrow*1024 + 512 + k]);
}

__global__ __launch_bounds__(512) void embed_k(const float* __restrict__ x,
    const float* __restrict__ wconv, unsigned short* __restrict__ out,
    int Bsz, int Lx, int l0, int lcount, int mode){
  __shared__ float wl[512*21];
  __shared__ float xl[66*7];
  int nch = (lcount + 63) / 64;
  int b = blockIdx.x / nch, ci = blockIdx.x % nch;
  int tid = threadIdx.x;
  for (int i = tid; i < 512*21; i += 512) wl[i] = wconv[i];
  int lstart = l0 + ci*64;
  int cnt = l0 + lcount - lstart; if (cnt > 64) cnt = 64;
  int nwin = (cnt + 2) * 7;
  for (int i = tid; i < nwin; i += 512){
    int wr = i / 7, c = i % 7;
    int gl = lstart - 1 + wr;
    gl = (gl + Lx) % Lx;
    xl[i] = x[((size_t)b*Lx + gl)*7 + c];
  }
  __syncthreads();
  int o = tid;
  float fe = (float)(o & ~1);
  float div = __expf(fe * -0.0179889461f);
  const float* wrow = &wl[o*21];
  for (int li = 0; li < cnt; ++li){
    int l = lstart + li;
    float acc = 0.f;
    #pragma unroll
    for (int c = 0; c < 7; ++c)
      #pragma unroll
      for (int kk = 0; kk < 3; ++kk)
        acc += xl[(li + kk)*7 + c] * wrow[c*3 + kk];
    float arg = (float)l * div;
    acc += (o & 1) ? cosf(arg) : sinf(arg);
    size_t oi = mode ? (((size_t)b*lcount + (l - l0))*512 + o)
                     : (((size_t)l*Bsz + b)*512 + o);
    out[oi] = f2bf(acc);
  }
}

// ----------------------------- bf16 NT GEMM (lda/ldb/ldc) ------------------
__global__ __launch_bounds__(256) void gemm_nt(const unsigned short* __restrict__ A, int lda,
    const unsigned short* __restrict__ Bw, int ldb, const float* __restrict__ bias,
    unsigned short* __restrict__ C, int ldc, int M, int N, int K){
  __shared__ __align__(16) unsigned short Asm[128*40];
  __shared__ __align__(16) unsigned short Bsm[128*40];
  const int tid = threadIdx.x;
  const int m0 = blockIdx.y * 128, n0 = blockIdx.x * 128;
  const int lane = tid & 63;
  const int wid = tid >> 6;
  const int wm = (wid >> 1) * 64, wn = (wid & 1) * 64;
  const int fr = lane & 15, q = lane >> 4;
  f32x4 acc[4][4];
  #pragma unroll
  for (int i=0;i<4;i++)
    #pragma unroll
    for(int j=0;j<4;j++) acc[i][j] = (f32x4){0.f,0.f,0.f,0.f};
  for (int k0 = 0; k0 < K; k0 += 32){
    #pragma unroll
    for (int c = 0; c < 2; ++c){
      int ch = tid + c*256;
      int r = ch >> 2, s = (ch & 3) * 8;
      *(uint4*)&Asm[r*40 + s] = *(const uint4*)&A[(size_t)(m0 + r)*lda + k0 + s];
      *(uint4*)&Bsm[r*40 + s] = *(const uint4*)&Bw[(size_t)(n0 + r)*ldb + k0 + s];
    }
    __syncthreads();
    bf16x8 af[4], bfv[4];
    #pragma unroll
    for (int i=0;i<4;i++){
      af[i]  = *(const bf16x8*)&Asm[(wm + i*16 + fr)*40 + q*8];
      bfv[i] = *(const bf16x8*)&Bsm[(wn + i*16 + fr)*40 + q*8];
    }
    #pragma unroll
    for (int i=0;i<4;i++)
      #pragma unroll
      for (int j=0;j<4;j++)
        acc[i][j] = __builtin_amdgcn_mfma_f32_16x16x32_bf16(af[i], bfv[j], acc[i][j], 0,0,0);
    __syncthreads();
  }
  #pragma unroll
  for (int i=0;i<4;i++){
    #pragma unroll
    for (int j=0;j<4;j++){
      int n = n0 + wn + j*16 + fr;
      float bv = bias ? bias[n] : 0.f;
      #pragma unroll
      for (int r=0;r<4;r++){
        int m = m0 + wm + i*16 + q*4 + r;
        C[(size_t)m*ldc + n] = f2bf(acc[i][j][r] + bv);
      }
    }
  }
}

// f32-output variant (for hWh)
__global__ __launch_bounds__(256) void gemm_ntf(const unsigned short* __restrict__ A, int lda,
    const unsigned short* __restrict__ Bw, int ldb,
    float* __restrict__ C, int ldc, int M, int N, int K){
  __shared__ __align__(16) unsigned short Asm[128*40];
  __shared__ __align__(16) unsigned short Bsm[128*40];
  const int tid = threadIdx.x;
  const int m0 = blockIdx.y * 128, n0 = blockIdx.x * 128;
  const int lane = tid & 63;
  const int wid = tid >> 6;
  const int wm = (wid >> 1) * 64, wn = (wid & 1) * 64;
  const int fr = lane & 15, q = lane >> 4;
  f32x4 acc[4][4];
  #pragma unroll
  for (int i=0;i<4;i++)
    #pragma unroll
    for(int j=0;j<4;j++) acc[i][j] = (f32x4){0.f,0.f,0.f,0.f};
  for (int k0 = 0; k0 < K; k0 += 32){
    #pragma unroll
    for (int c = 0; c < 2; ++c){
      int ch = tid + c*256;
      int r = ch >> 2, s = (ch & 3) * 8;
      *(uint4*)&Asm[r*40 + s] = *(const uint4*)&A[(size_t)(m0 + r)*lda + k0 + s];
      *(uint4*)&Bsm[r*40 + s] = *(const uint4*)&Bw[(size_t)(n0 + r)*ldb + k0 + s];
    }
    __syncthreads();
    bf16x8 af[4], bfv[4];
    #pragma unroll
    for (int i=0;i<4;i++){
      af[i]  = *(const bf16x8*)&Asm[(wm + i*16 + fr)*40 + q*8];
      bfv[i] = *(const bf16x8*)&Bsm[(wn + i*16 + fr)*40 + q*8];
    }
    #pragma unroll
    for (int i=0;i<4;i++)
      #pragma unroll
      for (int j=0;j<4;j++)
        acc[i][j] = __builtin_amdgcn_mfma_f32_16x16x32_bf16(af[i], bfv[j], acc[i][j], 0,0,0);
    __syncthreads();
  }
  #pragma unroll
  for (int i=0;i<4;i++){
    #pragma unroll
    for (int j=0;j<4;j++){
      int n = n0 + wn + j*16 + fr;
      #pragma unroll
      for (int r=0;r<4;r++){
        int m = m0 + wm + i*16 + q*4 + r;
        C[(size_t)m*ldc + n] = acc[i][j][r];
      }
    }
  }
}

// ----------------------------- LSTM device body ----------------------------
// 64 blocks = 4 batch-groups x 16 unit-blocks (32 units each, 512 threads).
// hbuf: [2 parity][64 batch][128 qwords]; qword = 2 bf16-pairs (4 units).
static __device__ __forceinline__ void lstm_body(char* smem, int lblk,
    const unsigned short* __restrict__ xw, const unsigned short* __restrict__ whh,
    float* __restrict__ cbuf, unsigned long long* __restrict__ hbuf,
    unsigned short* __restrict__ encout, int t0, int nsteps,
    unsigned* __restrict__ slots){
  unsigned short* wlds  = (unsigned short*)smem;                      // 128x516
  unsigned short* hblds = wlds + 128*516;                             // 16x516
  float* gbufE = (float*)(smem + (128*516 + 16*516)*2);               // 128x17
  const int tid = threadIdx.x;
  const int g = lblk >> 4, j = lblk & 15;
  const int b0 = g*16, u0 = j*32;
  for (int idx = tid; idx < 128*64; idx += 512){
    int n = idx >> 6, ch = idx & 63;
    int R = (n >> 5)*512 + u0 + (n & 31);
    *(uint4*)&wlds[n*516 + ch*8] = *(const uint4*)&whh[(size_t)R*512 + ch*8];
  }
  __syncthreads();
  const int lane = tid & 63, wv = tid >> 6, fr = lane & 15, q = lane >> 4;
  const int m = tid >> 5, j2 = tid & 31;
  float cst = cbuf[(b0 + m)*512 + u0 + j2];
  unsigned* myslot = slots + g*64 + j;
  const unsigned* gslots = slots + g*64;
  unsigned short px0, px1, px2, px3;
  {
    size_t xi = ((size_t)t0*64 + b0 + m)*2048 + u0 + j2;
    px0 = xw[xi]; px1 = xw[xi + 512]; px2 = xw[xi + 1024]; px3 = xw[xi + 1536];
  }
  for (int s = 0; s < nsteps; ++s){
    const int t = t0 + s;
    const int rp = t & 1, wp = rp ^ 1;
    {
      const unsigned long long* hq = hbuf + (size_t)rp*8192 + (size_t)b0*128;
      #pragma unroll
      for (int it = 0; it < 4; ++it){
        int idx = it*512 + tid;
        int b2 = idx >> 7, q2 = idx & 127;
        unsigned long long v = ldq(&hq[b2*128 + q2]);
        *(unsigned long long*)&hblds[b2*516 + q2*4] = v;
      }
    }
    __syncthreads();
    f32x4 acc = {0.f,0.f,0.f,0.f};
    #pragma unroll
    for (int k0 = 0; k0 < 512; k0 += 32){
      bf16x8 av = *(const bf16x8*)&hblds[fr*516 + k0 + q*8];
      bf16x8 bv = *(const bf16x8*)&wlds[(wv*16 + fr)*516 + k0 + q*8];
      acc = __builtin_amdgcn_mfma_f32_16x16x32_bf16(av, bv, acc, 0,0,0);
    }
    // acc[r] = C[batch=q*4+r][gate-row=wv*16+fr]
    #pragma unroll
    for (int r = 0; r < 4; ++r)
      gbufE[(wv*16 + fr)*17 + q*4 + r] = acc[r];
    __syncthreads();
    unsigned short hv;
    {
      float gi = gbufE[(j2)*17 + m]       + bf2f(px0);
      float gf = gbufE[(32 + j2)*17 + m]  + bf2f(px1);
      float gg = gbufE[(64 + j2)*17 + m]  + bf2f(px2);
      float go = gbufE[(96 + j2)*17 + m]  + bf2f(px3);
      float cc = sigm(gf)*cst + sigm(gi)*tanh2(gg);
      float hh = sigm(go)*tanh2(cc);
      cst = cc;
      hv = f2bf(hh);
      unsigned other = (unsigned)__shfl_xor((int)(unsigned)hv, 1);
      unsigned pair = ((unsigned)hv) | (other << 16);           // valid on even j2
      unsigned pair2 = (unsigned)__shfl_xor((int)pair, 2);      // units j2+2,j2+3
      if ((j2 & 3) == 0){
        unsigned long long qw = (((unsigned long long)pair2) << 32) | (unsigned long long)pair;
        stq(&hbuf[(size_t)wp*8192 + (size_t)(b0+m)*128 + ((u0 + j2) >> 2)], qw);
      }
    }
    VMWAIT();
    __syncthreads();
    if (tid == 0) stu(myslot, (unsigned)(t + 1));
    encout[((size_t)(b0+m)*512 + t)*512 + u0 + j2] = hv;
    if (s == nsteps - 1) cbuf[(b0+m)*512 + u0 + j2] = cst;
    else {
      size_t xi = ((size_t)(t+1)*64 + b0 + m)*2048 + u0 + j2;
      px0 = xw[xi]; px1 = xw[xi + 512]; px2 = xw[xi + 1024]; px3 = xw[xi + 1536];
    }
    if (tid < 64){
      unsigned target = (unsigned)(t + 1);
      bool mine = (tid < 16);
      while (true){
        bool ok = !mine || (ldu(&gslots[tid & 15]) >= target);
        if (__all(ok)) break;
        __builtin_amdgcn_s_sleep(1);
      }
    }
    __syncthreads();
  }
}

#define ENC_SMEM ((128*516 + 16*516)*2 + 128*17*4)

// plain lstm launch (phase B / dec uses same body via wrapper kernels)
__global__ __launch_bounds__(512) void lstm_enc(
    const unsigned short* __restrict__ xw, const unsigned short* __restrict__ whh,
    float* __restrict__ cbuf, unsigned long long* __restrict__ hbuf,
    unsigned short* __restrict__ encout, int t0, int nsteps,
    unsigned* __restrict__ slots){
  __shared__ __align__(16) char smem[ENC_SMEM];
  lstm_body(smem, blockIdx.x, xw, whh, cbuf, hbuf, encout, t0, nsteps, slots);
}

// phase A: blocks 0-63 = lstm steps [0,128); blocks 64+ = staging GEMM for
// steps [128,512): C[m][n] = A[m][k]*Bw[n][k] + bias[n], 512-thread tiles.
__global__ __launch_bounds__(512) void enc_fusedA(
    const unsigned short* __restrict__ xw, const unsigned short* __restrict__ whh,
    float* __restrict__ cbuf, unsigned long long* __restrict__ hbuf,
    unsigned short* __restrict__ encout, unsigned* __restrict__ slots,
    const unsigned short* __restrict__ gA, const unsigned short* __restrict__ gB,
    const float* __restrict__ gbias, unsigned short* __restrict__ gC){
  __shared__ __align__(16) char smem[ENC_SMEM];
  const int tid = threadIdx.x;
  if (blockIdx.x < 64){
    lstm_body(smem, blockIdx.x, xw, whh, cbuf, hbuf, encout, 0, 128, slots);
    return;
  }
  // ---- 512-thread GEMM tile: 128x128, 8 waves of 64m x 32n
  unsigned short* Asm = (unsigned short*)smem;        // 128x40
  unsigned short* Bsm = Asm + 128*40;                 // 128x40
  const int gblk = blockIdx.x - 64;                   // 0..3071
  const int m0 = (gblk >> 4)*128, n0 = (gblk & 15)*128;
  const int lane = tid & 63, wid = tid >> 6;
  const int wm = (wid >> 2)*64, wn = (wid & 3)*32;
  const int fr = lane & 15, q = lane >> 4;
  const int K = 512, N = 2048;
  f32x4 acc[4][2];
  #pragma unroll
  for (int i=0;i<4;i++)
    #pragma unroll
    for (int jj=0;jj<2;jj++) acc[i][jj] = (f32x4){0.f,0.f,0.f,0.f};
  for (int k0 = 0; k0 < K; k0 += 32){
    {
      int r = tid >> 2, s = (tid & 3)*8;
      *(uint4*)&Asm[r*40 + s] = *(const uint4*)&gA[(size_t)(m0 + r)*K + k0 + s];
      *(uint4*)&Bsm[r*40 + s] = *(const uint4*)&gB[(size_t)(n0 + r)*K + k0 + s];
    }
    __syncthreads();
    bf16x8 af[4], bfv[2];
    #pragma unroll
    for (int i=0;i<4;i++) af[i]  = *(const bf16x8*)&Asm[(wm + i*16 + fr)*40 + q*8];
    #pragma unroll
    for (int jj=0;jj<2;jj++) bfv[jj] = *(const bf16x8*)&Bsm[(wn + jj*16 + fr)*40 + q*8];
    #pragma unroll
    for (int i=0;i<4;i++)
      #pragma unroll
      for (int jj=0;jj<2;jj++)
        acc[i][jj] = __builtin_amdgcn_mfma_f32_16x16x32_bf16(af[i], bfv[jj], acc[i][jj], 0,0,0);
    __syncthreads();
  }
  #pragma unroll
  for (int i=0;i<4;i++){
    #pragma unroll
    for (int jj=0;jj<2;jj++){
      int n = n0 + wn + jj*16 + fr;
      float bv = gbias[n];
      #pragma unroll
      for (int r=0;r<4;r++){
        int m = m0 + wm + i*16 + q*4 + r;
        gC[(size_t)m*N + n] = f2bf(acc[i][jj][r] + bv);
      }
    }
  }
}

// ----------------------------- decoder LSTM (h-sequence only) --------------
__global__ __launch_bounds__(512) void dec_h(
    const unsigned short* __restrict__ xg,    // [64][48][2048] bf16 (bias folded)
    const unsigned short* __restrict__ whh,   // dec_Whh [2048][512] bf16
    const float* __restrict__ cbuf, unsigned long long* __restrict__ hbuf,
    unsigned short* __restrict__ X,           // [3072][1024]
    unsigned* __restrict__ slots){
  __shared__ __align__(16) unsigned short wlds[128*516];
  __shared__ __align__(16) unsigned short hblds[16*516];
  __shared__ float gbufE[128*17];
  const int tid = threadIdx.x;
  const int g = blockIdx.x >> 4, j = blockIdx.x & 15;
  const int b0 = g*16, u0 = j*32;
  for (int idx = tid; idx < 128*64; idx += 512){
    int n = idx >> 6, ch = idx & 63;
    int R = (n >> 5)*512 + u0 + (n & 31);
    *(uint4*)&wlds[n*516 + ch*8] = *(const uint4*)&whh[(size_t)R*512 + ch*8];
  }
  __syncthreads();
  const int lane = tid & 63, wv = tid >> 6, fr = lane & 15, q = lane >> 4;
  const int m = tid >> 5, j2 = tid & 31;
  float cst = cbuf[(b0 + m)*512 + u0 + j2];
  unsigned* myslot = slots + g*64 + j;
  const unsigned* gslots = slots + g*64;
  unsigned short px0, px1, px2, px3;
  {
    size_t xi = ((size_t)(b0 + m)*48)*2048 + u0 + j2;
    px0 = xg[xi]; px1 = xg[xi + 512]; px2 = xg[xi + 1024]; px3 = xg[xi + 1536];
  }
  for (int t = 0; t < 48; ++t){
    const int rp = t & 1, wp = rp ^ 1;
    {
      const unsigned long long* hq = hbuf + (size_t)rp*8192 + (size_t)b0*128;
      #pragma unroll
      for (int it = 0; it < 4; ++it){
        int idx = it*512 + tid;
        int b2 = idx >> 7, q2 = idx & 127;
        unsigned long long v = ldq(&hq[b2*128 + q2]);
        *(unsigned long long*)&hblds[b2*516 + q2*4] = v;
      }
    }
    __syncthreads();
    f32x4 acc = {0.f,0.f,0.f,0.f};
    #pragma unroll
    for (int k0 = 0; k0 < 512; k0 += 32){
      bf16x8 av = *(const bf16x8*)&hblds[fr*516 + k0 + q*8];
      bf16x8 bv = *(const bf16x8*)&wlds[(wv*16 + fr)*516 + k0 + q*8];
      acc = __builtin_amdgcn_mfma_f32_16x16x32_bf16(av, bv, acc, 0,0,0);
    }
    #pragma unroll
    for (int r = 0; r < 4; ++r)
      gbufE[(wv*16 + fr)*17 + q*4 + r] = acc[r];
    __syncthreads();
    unsigned short hv;
    {
      float gi = gbufE[(j2)*17 + m]       + bf2f(px0);
      float gf = gbufE[(32 + j2)*17 + m]  + bf2f(px1);
      float gg = gbufE[(64 + j2)*17 + m]  + bf2f(px2);
      float go = gbufE[(96 + j2)*17 + m]  + bf2f(px3);
      float cc = sigm(gf)*cst + sigm(gi)*tanh2(gg);
      float hh = sigm(go)*tanh2(cc);
      cst = cc;
      hv = f2bf(hh);
      unsigned other = (unsigned)__shfl_xor((int)(unsigned)hv, 1);
      unsigned pair = ((unsigned)hv) | (other << 16);
      unsigned pair2 = (unsigned)__shfl_xor((int)pair, 2);
      if ((j2 & 3) == 0){
        unsigned long long qw = (((unsigned long long)pair2) << 32) | (unsigned long long)pair;
        stq(&hbuf[(size_t)wp*8192 + (size_t)(b0+m)*128 + ((u0 + j2) >> 2)], qw);
      }
    }
    VMWAIT();
    __syncthreads();
    if (tid == 0) stu(myslot, (unsigned)(t + 1));
    X[((size_t)t*64 + b0 + m)*1024 + u0 + j2] = hv;
    if (t < 47){
      size_t xi = ((size_t)(b0 + m)*48 + t + 1)*2048 + u0 + j2;
      px0 = xg[xi]; px1 = xg[xi + 512]; px2 = xg[xi + 1024]; px3 = xg[xi + 1536];
    }
    if (tid < 64){
      unsigned target = (unsigned)(t + 1);
      bool mine = (tid < 16);
      while (true){
        bool ok = !mine || (ldu(&gslots[tid & 15]) >= target);
        if (__all(ok)) break;
        __builtin_amdgcn_s_sleep(1);
      }
    }
    __syncthreads();
  }
}

// ----------------------------- attention scores ----------------------------
__global__ __launch_bounds__(256) void attn_scores(
    const unsigned short* __restrict__ encpart, // [64*512][512]
    const float* __restrict__ hwh,              // [3072][512]
    const float* __restrict__ vvec,
    float* __restrict__ scores){                // [3072][512]
  __shared__ __align__(16) float hwhs[512];
  __shared__ __align__(16) float vm2s[512];
  __shared__ float red[4];
  const int tid = threadIdx.x;
  const int b = blockIdx.x >> 3, lc = blockIdx.x & 7;
  const int l = tid >> 2, kq = tid & 3;
  const int lane = tid & 63, wv = tid >> 6;
  vm2s[tid] = -2.f * vvec[tid];
  vm2s[tid+256] = -2.f * vvec[tid+256];
  __syncthreads();
  float vsumf;
  {
    float x = vm2s[tid] + vm2s[tid+256];
    #pragma unroll
    for (int off=32; off; off>>=1) x += __shfl_xor(x, off);
    if (lane == 0) red[wv] = x;
    __syncthreads();
    vsumf = -0.5f * (red[0]+red[1]+red[2]+red[3]);
  }
  bf16x8 epr[16];
  {
    const unsigned short* ep = encpart + ((size_t)(b*512 + lc*64 + l))*512 + kq*128;
    #pragma unroll
    for (int i = 0; i < 16; ++i) epr[i] = *(const bf16x8*)&ep[i*8];
  }
  const float C = 2.88539008f;
  for (int t = 0; t < 48; ++t){
    __syncthreads();
    hwhs[tid]     = C * hwh[((size_t)t*64 + b)*512 + tid];
    hwhs[tid+256] = C * hwh[((size_t)t*64 + b)*512 + tid + 256];
    __syncthreads();
    float sacc = 0.f;
    #pragma unroll
    for (int kk = 0; kk < 16; ++kk){
      float4 h0 = *(const float4*)&hwhs[kq*128 + kk*8];
      float4 h1 = *(const float4*)&hwhs[kq*128 + kk*8 + 4];
      float4 v0 = *(const float4*)&vm2s[kq*128 + kk*8];
      float4 v1 = *(const float4*)&vm2s[kq*128 + kk*8 + 4];
      const unsigned short* e = (const unsigned short*)&epr[kk];
      float hw[8] = {h0.x,h0.y,h0.z,h0.w,h1.x,h1.y,h1.z,h1.w};
      float vv[8] = {v0.x,v0.y,v0.z,v0.w,v1.x,v1.y,v1.z,v1.w};
      #pragma unroll
      for (int ee = 0; ee < 8; ++ee){
        float a = fmaf(bf2f(e[ee]), C, hw[ee]);
        sacc = fmaf(vv[ee], __builtin_amdgcn_rcpf(1.f + __builtin_amdgcn_exp2f(a)), sacc);
      }
    }
    sacc += __shfl_xor(sacc, 1);
    sacc += __shfl_xor(sacc, 2);
    if (kq == 0) scores[((size_t)t*64 + b)*512 + lc*64 + l] = vsumf + sacc;
  }
}

// ----------------------------- softmax -> aw (bf16) ------------------------
__global__ __launch_bounds__(256) void softmax_aw(
    const float* __restrict__ scores, unsigned short* __restrict__ awb){
  __shared__ float red[4];
  const int row = blockIdx.x, tid = threadIdx.x;
  const int lane = tid & 63, wv = tid >> 6;
  float v0 = scores[(size_t)row*512 + tid];
  float v1 = scores[(size_t)row*512 + tid + 256];
  float mx = fmaxf(v0, v1);
  #pragma unroll
  for (int off=32; off; off>>=1) mx = fmaxf(mx, __shfl_xor(mx, off));
  if (lane == 0) red[wv] = mx;
  __syncthreads();
  mx = fmaxf(fmaxf(red[0],red[1]), fmaxf(red[2],red[3]));
  __syncthreads();
  float e0 = __expf(v0 - mx), e1 = __expf(v1 - mx);
  float ps = e0 + e1;
  #pragma unroll
  for (int off=32; off; off>>=1) ps += __shfl_xor(ps, off);
  if (lane == 0) red[wv] = ps;
  __syncthreads();
  float inv = 1.f / (red[0]+red[1]+red[2]+red[3]);
  awb[(size_t)row*512 + tid]       = f2bf(e0 * inv);
  awb[(size_t)row*512 + tid + 256] = f2bf(e1 * inv);
}

// ----------------------------- ctx weighted sum ----------------------------
__global__ __launch_bounds__(256) void ctx_k(
    const unsigned short* __restrict__ awb,     // [3072][512]
    const unsigned short* __restrict__ encout,  // [64*512][512]
    unsigned short* __restrict__ X){
  __shared__ unsigned short awt[512*12];   // [l][tt]
  const int tid = threadIdx.x;
  const int b = blockIdx.x >> 2, t0 = (blockIdx.x & 3)*12;
  for (int i = tid; i < 12*256; i += 256){
    int tt = i >> 8, d = i & 255;
    unsigned u = *(const unsigned*)&awb[((size_t)(t0+tt)*64 + b)*512 + d*2];
    awt[(2*d)*12 + tt]   = (unsigned short)(u & 0xffffu);
    awt[(2*d+1)*12 + tt] = (unsigned short)(u >> 16);
  }
  __syncthreads();
  float a0[12], a1[12];
  #pragma unroll
  for (int j = 0; j < 12; ++j){ a0[j] = 0.f; a1[j] = 0.f; }
  const unsigned* eo = (const unsigned*)(encout + (size_t)b*512*512) + tid;
  for (int ll = 0; ll < 512; ++ll){
    unsigned ee = eo[(size_t)ll*256];
    float e0 = __uint_as_float((ee & 0xffffu) << 16);
    float e1 = __uint_as_float(ee & 0xffff0000u);
    const unsigned* wp2 = (const unsigned*)&awt[ll*12];
    float w[12];
    #pragma unroll
    for (int z = 0; z < 6; ++z){
      unsigned wu = wp2[z];
      w[2*z]   = bf2f((unsigned short)(wu & 0xffffu));
      w[2*z+1] = bf2f((unsigned short)(wu >> 16));
    }
    #pragma unroll
    for (int j = 0; j < 12; ++j){
      a0[j] = fmaf(w[j], e0, a0[j]);
      a1[j] = fmaf(w[j], e1, a1[j]);
    }
  }
  #pragma unroll
  for (int j = 0; j < 12; ++j){
    size_t r = (size_t)(t0+j)*64 + b;
    unsigned pk = ((unsigned)f2bf(a0[j])) | (((unsigned)f2bf(a1[j])) << 16);
    *(unsigned*)&X[r*1024 + 512 + 2*tid] = pk;
  }
}

// ----------------------------- projection ----------------------------------
__global__ void proj_k(const unsigned short* __restrict__ outs,
                       const float* __restrict__ pw, const float* __restrict__ pb,
                       float* __restrict__ out){
  int gid = blockIdx.x*256 + threadIdx.x;
  if (gid >= 64*48*7) return;
  int r = gid / 7, oc = gid % 7;
  int b = r & 63, t = r >> 6;
  const unsigned short* orow = outs + (size_t)r*512;
  const float* wrow = pw + oc*512;
  float s = pb[oc];
  for (int k = 0; k < 512; k += 8){
    bf16x8 o8 = *(const bf16x8*)&orow[k];
    #pragma unroll
    for (int e=0;e<8;e++) s += bf2f(((unsigned short*)&o8)[e]) * wrow[k+e];
  }
  out[((size_t)b*48 + t)*7 + oc] = s;
}

// ----------------------------- launch --------------------------------------
extern "C" void kernel_launch(void* const* d_in, const int* in_sizes, int n_in,
                              void* d_out, int out_size, void* d_ws, size_t ws_size,
                              hipStream_t stream){
  (void)in_sizes; (void)n_in; (void)out_size; (void)ws_size;
  const float* x_enc   = (const float*)d_in[0];
  const float* x_dec   = (const float*)d_in[1];
  const float* w_emb_e = (const float*)d_in[2];
  const float* w_emb_d = (const float*)d_in[3];
  const float* enc_Wih = (const float*)d_in[4];
  const float* enc_Whh = (const float*)d_in[5];
  const float* enc_b   = (const float*)d_in[6];
  const float* dec_Wih = (const float*)d_in[7];
  const float* dec_Whh = (const float*)d_in[8];
  const float* dec_b   = (const float*)d_in[9];
  const float* attn_W  = (const float*)d_in[10];
  const float* attn_b  = (const float*)d_in[11];
  const float* vvec    = (const float*)d_in[12];
  const float* fc_W    = (const float*)d_in[13];
  const float* fc_b    = (const float*)d_in[14];
  const float* proj_W  = (const float*)d_in[15];
  const float* proj_b  = (const float*)d_in[16];
  float* out = (float*)d_out;

  char* ws = (char*)d_ws;
  size_t off = 0;
  auto alloc = [&](size_t bytes)->char*{
    char* p = ws + off;
    off = (off + bytes + 255) & ~(size_t)255;
    return p;
  };
  unsigned short* encxw  = (unsigned short*)alloc(512ull*64*2048*2); // all steps
  unsigned short* encin  = (unsigned short*)alloc(512ull*64*512*2);  // embed; reused as enc_part
  unsigned short* encout = (unsigned short*)alloc(64ull*512*512*2);
  unsigned short* xs     = (unsigned short*)alloc(64ull*48*512*2);
  unsigned short* xg     = (unsigned short*)alloc(64ull*48*2048*2);
  unsigned short* Xb     = (unsigned short*)alloc(3072ull*1024*2);
  float* hwh    = (float*)alloc(3072ull*512*4);
  float* scores = (float*)alloc(3072ull*512*4);
  unsigned short* awb    = (unsigned short*)alloc(3072ull*512*2);
  unsigned short* outsb  = (unsigned short*)alloc(3072ull*512*2);
  unsigned short* wih_e  = (unsigned short*)alloc(2048ull*512*2);
  unsigned short* whh_e  = (unsigned short*)alloc(2048ull*512*2);
  unsigned short* wih_d  = (unsigned short*)alloc(2048ull*512*2);
  unsigned short* whh_d  = (unsigned short*)alloc(2048ull*512*2);
  unsigned short* whq    = (unsigned short*)alloc(512ull*512*2);
  unsigned short* weq    = (unsigned short*)alloc(512ull*512*2);
  unsigned short* fcw    = (unsigned short*)alloc(512ull*1024*2);
  unsigned long long* hbuf = (unsigned long long*)alloc(2ull*64*128*8);
  float* cbuf   = (float*)alloc(64ull*512*4);
  unsigned* eslots = (unsigned*)alloc(4*64*4);
  unsigned* dslots = (unsigned*)alloc(4*64*4);

  hipMemsetAsync(hbuf, 0, 2ull*64*128*8, stream);
  hipMemsetAsync(cbuf, 0, 64ull*512*4, stream);
  hipMemsetAsync(eslots, 0, 4*64*4, stream);
  hipMemsetAsync(dslots, 0, 4*64*4, stream);

  cast_k<<<4096, 256, 0, stream>>>(enc_Wih, wih_e, 2048*512);
  cast_k<<<4096, 256, 0, stream>>>(enc_Whh, whh_e, 2048*512);
  cast_k<<<4096, 256, 0, stream>>>(dec_Wih, wih_d, 2048*512);
  cast_k<<<4096, 256, 0, stream>>>(dec_Whh, whh_d, 2048*512);
  cast_k<<<2048, 256, 0, stream>>>(fc_W, fcw, 512*1024);
  split_attn_k<<<1024, 256, 0, stream>>>(attn_W, whq, weq);

  embed_k<<<512, 512, 0, stream>>>(x_enc, w_emb_e, encin, 64, 512, 0, 512, 0);
  embed_k<<<64, 512, 0, stream>>>(x_dec, w_emb_d, xs, 64, 144, 48, 48, 1);

  // xg = xs @ dec_Wih^T + dec_b   [3072][2048]
  gemm_nt<<<dim3(16, 24), 256, 0, stream>>>(xs, 512, wih_d, 512, dec_b, xg, 2048, 3072, 2048, 512);

  // staging gemm for steps [0,128) only
  gemm_nt<<<dim3(16, 64), 256, 0, stream>>>(encin, 512, wih_e, 512, enc_b, encxw, 2048, 8192, 2048, 512);
  // phase A: lstm steps [0,128) + fused staging gemm for steps [128,512)
  enc_fusedA<<<64 + 3072, 512, 0, stream>>>(encxw, whh_e, cbuf, hbuf, encout, eslots,
                                            encin + (size_t)8192*512, wih_e, enc_b,
                                            encxw + (size_t)8192*2048);
  // phase B: lstm steps [128,512)
  lstm_enc<<<64, 512, 0, stream>>>(encxw, whh_e, cbuf, hbuf, encout, 128, 384, eslots);

  // enc_part = encout @ We^T + attn_b  (reuses encin buffer)
  gemm_nt<<<dim3(4, 256), 256, 0, stream>>>(encout, 512, weq, 512, attn_b, encin, 512, 32768, 512, 512);

  // decoder LSTM h-sequence -> X[:, :512]
  dec_h<<<64, 512, 0, stream>>>(xg, whh_d, cbuf, hbuf, Xb, dslots);

  // hWh = h @ Wh^T  (f32)
  gemm_ntf<<<dim3(4, 24), 256, 0, stream>>>(Xb, 1024, whq, 512, hwh, 512, 3072, 512, 512);

  // scores, softmax, ctx
  attn_scores<<<512, 256, 0, stream>>>(encin /*enc_part*/, hwh, vvec, scores);
  softmax_aw<<<3072, 256, 0, stream>>>(scores, awb);
  ctx_k<<<256, 256, 0, stream>>>(awb, encout, Xb);

  // fc: [h|ctx] @ fc_W^T + fc_b
  gemm_nt<<<dim3(4, 24), 256, 0, stream>>>(Xb, 1024, fcw, 1024, fc_b, outsb, 512, 3072, 512, 1024);

  proj_k<<<84, 256, 0, stream>>>(outsb, proj_W, proj_b, out);
}

// Round 16
// 2770.413 us; speedup vs baseline: 2.0840x; 2.0840x over previous
//
#include <hip/hip_runtime.h>
#include <hip/hip_bf16.h>

// ---------------------------------------------------------------------------
// conv1d embed -> LSTM encoder (512 steps, B=64, H=512) -> decoder (decoupled
// h-recurrence + batched attention) -> projection.
// r16 = r14 revert (best verified config, 2779 us). r15's GEMM-under-LSTM
// fusion regressed 2x: fused GEMM blocks inherit 157 KB LDS (1 block/CU) and
// their memory traffic inflates every latency-bound recurrence step ~2.5x.
// Rule confirmed three times (r5, r9, r15): the h-exchange tolerates no
// background traffic.
// ---------------------------------------------------------------------------

typedef short bf16x8 __attribute__((ext_vector_type(8)));
typedef float f32x4 __attribute__((ext_vector_type(4)));

static __device__ __forceinline__ float bf2f(unsigned short u){
  return __uint_as_float(((unsigned)u) << 16);
}
static __device__ __forceinline__ unsigned short f2bf(float f){
  unsigned x = __float_as_uint(f);
  return (unsigned short)((x + 0x7fffu + ((x >> 16) & 1u)) >> 16);   // RNE
}
static __device__ __forceinline__ float sigm(float x){
  return __builtin_amdgcn_rcpf(1.f + __builtin_amdgcn_exp2f(-1.44269504f*x));
}
static __device__ __forceinline__ float tanh2(float x){
  return 1.f - 2.f*__builtin_amdgcn_rcpf(1.f + __builtin_amdgcn_exp2f(2.88539008f*x));
}

static __device__ __forceinline__ unsigned ldu(const unsigned* p){
  return __hip_atomic_load(p, __ATOMIC_RELAXED, __HIP_MEMORY_SCOPE_AGENT);
}
static __device__ __forceinline__ void stu(unsigned* p, unsigned v){
  __hip_atomic_store(p, v, __ATOMIC_RELAXED, __HIP_MEMORY_SCOPE_AGENT);
}
static __device__ __forceinline__ unsigned long long ldq(const unsigned long long* p){
  return __hip_atomic_load(p, __ATOMIC_RELAXED, __HIP_MEMORY_SCOPE_AGENT);
}
static __device__ __forceinline__ void stq(unsigned long long* p, unsigned long long v){
  __hip_atomic_store(p, v, __ATOMIC_RELAXED, __HIP_MEMORY_SCOPE_AGENT);
}
#define VMWAIT() __asm__ __volatile__("s_waitcnt vmcnt(0)" ::: "memory")

// ----------------------------- small utility kernels -----------------------

__global__ void cast_k(const float* __restrict__ src, unsigned short* __restrict__ dst, int n){
  int i = blockIdx.x*256 + threadIdx.x;
  if (i < n) dst[i] = f2bf(src[i]);
}

__global__ void split_attn_k(const float* __restrict__ aw,
                             unsigned short* __restrict__ wh, unsigned short* __restrict__ we){
  int i = blockIdx.x*256 + threadIdx.x;
  int nrow = i >> 9, k = i & 511;
  wh[i] = f2bf(aw[(size_t)nrow*1024 + k]);
  we[i] = f2bf(aw[(size_t)nrow*1024 + 512 + k]);
}

__global__ __launch_bounds__(512) void embed_k(const float* __restrict__ x,
    const float* __restrict__ wconv, unsigned short* __restrict__ out,
    int Bsz, int Lx, int l0, int lcount, int mode){
  __shared__ float wl[512*21];
  __shared__ float xl[66*7];
  int nch = (lcount + 63) / 64;
  int b = blockIdx.x / nch, ci = blockIdx.x % nch;
  int tid = threadIdx.x;
  for (int i = tid; i < 512*21; i += 512) wl[i] = wconv[i];
  int lstart = l0 + ci*64;
  int cnt = l0 + lcount - lstart; if (cnt > 64) cnt = 64;
  int nwin = (cnt + 2) * 7;
  for (int i = tid; i < nwin; i += 512){
    int wr = i / 7, c = i % 7;
    int gl = lstart - 1 + wr;
    gl = (gl + Lx) % Lx;
    xl[i] = x[((size_t)b*Lx + gl)*7 + c];
  }
  __syncthreads();
  int o = tid;
  float fe = (float)(o & ~1);
  float div = __expf(fe * -0.0179889461f);
  const float* wrow = &wl[o*21];
  for (int li = 0; li < cnt; ++li){
    int l = lstart + li;
    float acc = 0.f;
    #pragma unroll
    for (int c = 0; c < 7; ++c)
      #pragma unroll
      for (int kk = 0; kk < 3; ++kk)
        acc += xl[(li + kk)*7 + c] * wrow[c*3 + kk];
    float arg = (float)l * div;
    acc += (o & 1) ? cosf(arg) : sinf(arg);
    size_t oi = mode ? (((size_t)b*lcount + (l - l0))*512 + o)
                     : (((size_t)l*Bsz + b)*512 + o);
    out[oi] = f2bf(acc);
  }
}

// ----------------------------- bf16 NT GEMM (lda/ldb/ldc) ------------------
__global__ __launch_bounds__(256) void gemm_nt(const unsigned short* __restrict__ A, int lda,
    const unsigned short* __restrict__ Bw, int ldb, const float* __restrict__ bias,
    unsigned short* __restrict__ C, int ldc, int M, int N, int K){
  __shared__ __align__(16) unsigned short Asm[128*40];
  __shared__ __align__(16) unsigned short Bsm[128*40];
  const int tid = threadIdx.x;
  const int m0 = blockIdx.y * 128, n0 = blockIdx.x * 128;
  const int lane = tid & 63;
  const int wid = tid >> 6;
  const int wm = (wid >> 1) * 64, wn = (wid & 1) * 64;
  const int fr = lane & 15, q = lane >> 4;
  f32x4 acc[4][4];
  #pragma unroll
  for (int i=0;i<4;i++)
    #pragma unroll
    for(int j=0;j<4;j++) acc[i][j] = (f32x4){0.f,0.f,0.f,0.f};
  for (int k0 = 0; k0 < K; k0 += 32){
    #pragma unroll
    for (int c = 0; c < 2; ++c){
      int ch = tid + c*256;
      int r = ch >> 2, s = (ch & 3) * 8;
      *(uint4*)&Asm[r*40 + s] = *(const uint4*)&A[(size_t)(m0 + r)*lda + k0 + s];
      *(uint4*)&Bsm[r*40 + s] = *(const uint4*)&Bw[(size_t)(n0 + r)*ldb + k0 + s];
    }
    __syncthreads();
    bf16x8 af[4], bfv[4];
    #pragma unroll
    for (int i=0;i<4;i++){
      af[i]  = *(const bf16x8*)&Asm[(wm + i*16 + fr)*40 + q*8];
      bfv[i] = *(const bf16x8*)&Bsm[(wn + i*16 + fr)*40 + q*8];
    }
    #pragma unroll
    for (int i=0;i<4;i++)
      #pragma unroll
      for (int j=0;j<4;j++)
        acc[i][j] = __builtin_amdgcn_mfma_f32_16x16x32_bf16(af[i], bfv[j], acc[i][j], 0,0,0);
    __syncthreads();
  }
  #pragma unroll
  for (int i=0;i<4;i++){
    #pragma unroll
    for (int j=0;j<4;j++){
      int n = n0 + wn + j*16 + fr;
      float bv = bias ? bias[n] : 0.f;
      #pragma unroll
      for (int r=0;r<4;r++){
        int m = m0 + wm + i*16 + q*4 + r;
        C[(size_t)m*ldc + n] = f2bf(acc[i][j][r] + bv);
      }
    }
  }
}

// f32-output variant (for hWh)
__global__ __launch_bounds__(256) void gemm_ntf(const unsigned short* __restrict__ A, int lda,
    const unsigned short* __restrict__ Bw, int ldb,
    float* __restrict__ C, int ldc, int M, int N, int K){
  __shared__ __align__(16) unsigned short Asm[128*40];
  __shared__ __align__(16) unsigned short Bsm[128*40];
  const int tid = threadIdx.x;
  const int m0 = blockIdx.y * 128, n0 = blockIdx.x * 128;
  const int lane = tid & 63;
  const int wid = tid >> 6;
  const int wm = (wid >> 1) * 64, wn = (wid & 1) * 64;
  const int fr = lane & 15, q = lane >> 4;
  f32x4 acc[4][4];
  #pragma unroll
  for (int i=0;i<4;i++)
    #pragma unroll
    for(int j=0;j<4;j++) acc[i][j] = (f32x4){0.f,0.f,0.f,0.f};
  for (int k0 = 0; k0 < K; k0 += 32){
    #pragma unroll
    for (int c = 0; c < 2; ++c){
      int ch = tid + c*256;
      int r = ch >> 2, s = (ch & 3) * 8;
      *(uint4*)&Asm[r*40 + s] = *(const uint4*)&A[(size_t)(m0 + r)*lda + k0 + s];
      *(uint4*)&Bsm[r*40 + s] = *(const uint4*)&Bw[(size_t)(n0 + r)*ldb + k0 + s];
    }
    __syncthreads();
    bf16x8 af[4], bfv[4];
    #pragma unroll
    for (int i=0;i<4;i++){
      af[i]  = *(const bf16x8*)&Asm[(wm + i*16 + fr)*40 + q*8];
      bfv[i] = *(const bf16x8*)&Bsm[(wn + i*16 + fr)*40 + q*8];
    }
    #pragma unroll
    for (int i=0;i<4;i++)
      #pragma unroll
      for (int j=0;j<4;j++)
        acc[i][j] = __builtin_amdgcn_mfma_f32_16x16x32_bf16(af[i], bfv[j], acc[i][j], 0,0,0);
    __syncthreads();
  }
  #pragma unroll
  for (int i=0;i<4;i++){
    #pragma unroll
    for (int j=0;j<4;j++){
      int n = n0 + wn + j*16 + fr;
      #pragma unroll
      for (int r=0;r<4;r++){
        int m = m0 + wm + i*16 + q*4 + r;
        C[(size_t)m*ldc + n] = acc[i][j][r];
      }
    }
  }
}

// ----------------------------- encoder LSTM --------------------------------
// 64 blocks = 4 batch-groups x 16 unit-blocks (32 units each, 512 threads).
// hbuf: [2 parity][64 batch][128 qwords]; qword = 2 bf16-pairs (4 units).
__global__ __launch_bounds__(512) void lstm_enc(
    const unsigned short* __restrict__ xw,    // [nsteps][64][2048] bf16 (bias folded)
    const unsigned short* __restrict__ whh,   // [2048][512] bf16
    float* __restrict__ cbuf, unsigned long long* __restrict__ hbuf,
    unsigned short* __restrict__ encout,      // [64][512][512]
    int t0, int nsteps, unsigned* __restrict__ slots){
  __shared__ __align__(16) unsigned short wlds[128*516];
  __shared__ __align__(16) unsigned short hblds[16*516];
  __shared__ float gbufE[128*17];
  const int tid = threadIdx.x;
  const int g = blockIdx.x >> 4, j = blockIdx.x & 15;
  const int b0 = g*16, u0 = j*32;
  // weight rows n=0..127: gate = n>>5, unit = u0 + (n&31)
  for (int idx = tid; idx < 128*64; idx += 512){
    int n = idx >> 6, ch = idx & 63;
    int R = (n >> 5)*512 + u0 + (n & 31);
    *(uint4*)&wlds[n*516 + ch*8] = *(const uint4*)&whh[(size_t)R*512 + ch*8];
  }
  __syncthreads();
  const int lane = tid & 63, wv = tid >> 6, fr = lane & 15, q = lane >> 4;
  const int m = tid >> 5, j2 = tid & 31;
  float cst = cbuf[(b0 + m)*512 + u0 + j2];
  unsigned* myslot = slots + g*64 + j;
  const unsigned* gslots = slots + g*64;
  unsigned short px0, px1, px2, px3;
  {
    size_t xi = ((size_t)t0*64 + b0 + m)*2048 + u0 + j2;
    px0 = xw[xi]; px1 = xw[xi + 512]; px2 = xw[xi + 1024]; px3 = xw[xi + 1536];
  }
  for (int s = 0; s < nsteps; ++s){
    const int t = t0 + s;
    const int rp = t & 1, wp = rp ^ 1;
    // stage h(group): 2048 qwords over 512 threads
    {
      const unsigned long long* hq = hbuf + (size_t)rp*8192 + (size_t)b0*128;
      #pragma unroll
      for (int it = 0; it < 4; ++it){
        int idx = it*512 + tid;
        int b2 = idx >> 7, q2 = idx & 127;
        unsigned long long v = ldq(&hq[b2*128 + q2]);
        *(unsigned long long*)&hblds[b2*516 + q2*4] = v;
      }
    }
    __syncthreads();
    f32x4 acc = {0.f,0.f,0.f,0.f};
    #pragma unroll
    for (int k0 = 0; k0 < 512; k0 += 32){
      bf16x8 av = *(const bf16x8*)&hblds[fr*516 + k0 + q*8];
      bf16x8 bv = *(const bf16x8*)&wlds[(wv*16 + fr)*516 + k0 + q*8];
      acc = __builtin_amdgcn_mfma_f32_16x16x32_bf16(av, bv, acc, 0,0,0);
    }
    // acc[r] = C[batch=q*4+r][gate-row=wv*16+fr]
    #pragma unroll
    for (int r = 0; r < 4; ++r)
      gbufE[(wv*16 + fr)*17 + q*4 + r] = acc[r];
    __syncthreads();
    unsigned short hv;
    {
      float gi = gbufE[(j2)*17 + m]       + bf2f(px0);
      float gf = gbufE[(32 + j2)*17 + m]  + bf2f(px1);
      float gg = gbufE[(64 + j2)*17 + m]  + bf2f(px2);
      float go = gbufE[(96 + j2)*17 + m]  + bf2f(px3);
      float cc = sigm(gf)*cst + sigm(gi)*tanh2(gg);
      float hh = sigm(go)*tanh2(cc);
      cst = cc;
      hv = f2bf(hh);
      unsigned other = (unsigned)__shfl_xor((int)(unsigned)hv, 1);
      unsigned pair = ((unsigned)hv) | (other << 16);           // valid on even j2
      unsigned pair2 = (unsigned)__shfl_xor((int)pair, 2);      // units j2+2,j2+3
      if ((j2 & 3) == 0){
        unsigned long long qw = (((unsigned long long)pair2) << 32) | (unsigned long long)pair;
        stq(&hbuf[(size_t)wp*8192 + (size_t)(b0+m)*128 + ((u0 + j2) >> 2)], qw);
      }
    }
    // arrive early: publish h (drained), then non-critical work, then wait
    VMWAIT();
    __syncthreads();
    if (tid == 0) stu(myslot, (unsigned)(t + 1));
    encout[((size_t)(b0+m)*512 + t)*512 + u0 + j2] = hv;
    if (s == nsteps - 1) cbuf[(b0+m)*512 + u0 + j2] = cst;
    else {
      size_t xi = ((size_t)(t+1)*64 + b0 + m)*2048 + u0 + j2;
      px0 = xw[xi]; px1 = xw[xi + 512]; px2 = xw[xi + 1024]; px3 = xw[xi + 1536];
    }
    if (tid < 64){
      unsigned target = (unsigned)(t + 1);
      bool mine = (tid < 16);
      while (true){
        bool ok = !mine || (ldu(&gslots[tid & 15]) >= target);
        if (__all(ok)) break;
        __builtin_amdgcn_s_sleep(1);
      }
    }
    __syncthreads();
  }
}

// ----------------------------- decoder LSTM (h-sequence only) --------------
__global__ __launch_bounds__(512) void dec_h(
    const unsigned short* __restrict__ xg,    // [64][48][2048] bf16 (bias folded)
    const unsigned short* __restrict__ whh,   // dec_Whh [2048][512] bf16
    const float* __restrict__ cbuf, unsigned long long* __restrict__ hbuf,
    unsigned short* __restrict__ X,           // [3072][1024]
    unsigned* __restrict__ slots){
  __shared__ __align__(16) unsigned short wlds[128*516];
  __shared__ __align__(16) unsigned short hblds[16*516];
  __shared__ float gbufE[128*17];
  const int tid = threadIdx.x;
  const int g = blockIdx.x >> 4, j = blockIdx.x & 15;
  const int b0 = g*16, u0 = j*32;
  for (int idx = tid; idx < 128*64; idx += 512){
    int n = idx >> 6, ch = idx & 63;
    int R = (n >> 5)*512 + u0 + (n & 31);
    *(uint4*)&wlds[n*516 + ch*8] = *(const uint4*)&whh[(size_t)R*512 + ch*8];
  }
  __syncthreads();
  const int lane = tid & 63, wv = tid >> 6, fr = lane & 15, q = lane >> 4;
  const int m = tid >> 5, j2 = tid & 31;
  float cst = cbuf[(b0 + m)*512 + u0 + j2];
  unsigned* myslot = slots + g*64 + j;
  const unsigned* gslots = slots + g*64;
  unsigned short px0, px1, px2, px3;
  {
    size_t xi = ((size_t)(b0 + m)*48)*2048 + u0 + j2;
    px0 = xg[xi]; px1 = xg[xi + 512]; px2 = xg[xi + 1024]; px3 = xg[xi + 1536];
  }
  for (int t = 0; t < 48; ++t){
    const int rp = t & 1, wp = rp ^ 1;
    {
      const unsigned long long* hq = hbuf + (size_t)rp*8192 + (size_t)b0*128;
      #pragma unroll
      for (int it = 0; it < 4; ++it){
        int idx = it*512 + tid;
        int b2 = idx >> 7, q2 = idx & 127;
        unsigned long long v = ldq(&hq[b2*128 + q2]);
        *(unsigned long long*)&hblds[b2*516 + q2*4] = v;
      }
    }
    __syncthreads();
    f32x4 acc = {0.f,0.f,0.f,0.f};
    #pragma unroll
    for (int k0 = 0; k0 < 512; k0 += 32){
      bf16x8 av = *(const bf16x8*)&hblds[fr*516 + k0 + q*8];
      bf16x8 bv = *(const bf16x8*)&wlds[(wv*16 + fr)*516 + k0 + q*8];
      acc = __builtin_amdgcn_mfma_f32_16x16x32_bf16(av, bv, acc, 0,0,0);
    }
    #pragma unroll
    for (int r = 0; r < 4; ++r)
      gbufE[(wv*16 + fr)*17 + q*4 + r] = acc[r];
    __syncthreads();
    unsigned short hv;
    {
      float gi = gbufE[(j2)*17 + m]       + bf2f(px0);
      float gf = gbufE[(32 + j2)*17 + m]  + bf2f(px1);
      float gg = gbufE[(64 + j2)*17 + m]  + bf2f(px2);
      float go = gbufE[(96 + j2)*17 + m]  + bf2f(px3);
      float cc = sigm(gf)*cst + sigm(gi)*tanh2(gg);
      float hh = sigm(go)*tanh2(cc);
      cst = cc;
      hv = f2bf(hh);
      unsigned other = (unsigned)__shfl_xor((int)(unsigned)hv, 1);
      unsigned pair = ((unsigned)hv) | (other << 16);
      unsigned pair2 = (unsigned)__shfl_xor((int)pair, 2);
      if ((j2 & 3) == 0){
        unsigned long long qw = (((unsigned long long)pair2) << 32) | (unsigned long long)pair;
        stq(&hbuf[(size_t)wp*8192 + (size_t)(b0+m)*128 + ((u0 + j2) >> 2)], qw);
      }
    }
    VMWAIT();
    __syncthreads();
    if (tid == 0) stu(myslot, (unsigned)(t + 1));
    X[((size_t)t*64 + b0 + m)*1024 + u0 + j2] = hv;
    if (t < 47){
      size_t xi = ((size_t)(b0 + m)*48 + t + 1)*2048 + u0 + j2;
      px0 = xg[xi]; px1 = xg[xi + 512]; px2 = xg[xi + 1024]; px3 = xg[xi + 1536];
    }
    if (tid < 64){
      unsigned target = (unsigned)(t + 1);
      bool mine = (tid < 16);
      while (true){
        bool ok = !mine || (ldu(&gslots[tid & 15]) >= target);
        if (__all(ok)) break;
        __builtin_amdgcn_s_sleep(1);
      }
    }
    __syncthreads();
  }
}

// ----------------------------- attention scores ----------------------------
__global__ __launch_bounds__(256) void attn_scores(
    const unsigned short* __restrict__ encpart, // [64*512][512]
    const float* __restrict__ hwh,              // [3072][512]
    const float* __restrict__ vvec,
    float* __restrict__ scores){                // [3072][512]
  __shared__ __align__(16) float hwhs[512];
  __shared__ __align__(16) float vm2s[512];
  __shared__ float red[4];
  const int tid = threadIdx.x;
  const int b = blockIdx.x >> 3, lc = blockIdx.x & 7;
  const int l = tid >> 2, kq = tid & 3;
  const int lane = tid & 63, wv = tid >> 6;
  vm2s[tid] = -2.f * vvec[tid];
  vm2s[tid+256] = -2.f * vvec[tid+256];
  __syncthreads();
  float vsumf;
  {
    float x = vm2s[tid] + vm2s[tid+256];
    #pragma unroll
    for (int off=32; off; off>>=1) x += __shfl_xor(x, off);
    if (lane == 0) red[wv] = x;
    __syncthreads();
    vsumf = -0.5f * (red[0]+red[1]+red[2]+red[3]);
  }
  bf16x8 epr[16];
  {
    const unsigned short* ep = encpart + ((size_t)(b*512 + lc*64 + l))*512 + kq*128;
    #pragma unroll
    for (int i = 0; i < 16; ++i) epr[i] = *(const bf16x8*)&ep[i*8];
  }
  const float C = 2.88539008f;
  for (int t = 0; t < 48; ++t){
    __syncthreads();
    hwhs[tid]     = C * hwh[((size_t)t*64 + b)*512 + tid];
    hwhs[tid+256] = C * hwh[((size_t)t*64 + b)*512 + tid + 256];
    __syncthreads();
    float sacc = 0.f;
    #pragma unroll
    for (int kk = 0; kk < 16; ++kk){
      float4 h0 = *(const float4*)&hwhs[kq*128 + kk*8];
      float4 h1 = *(const float4*)&hwhs[kq*128 + kk*8 + 4];
      float4 v0 = *(const float4*)&vm2s[kq*128 + kk*8];
      float4 v1 = *(const float4*)&vm2s[kq*128 + kk*8 + 4];
      const unsigned short* e = (const unsigned short*)&epr[kk];
      float hw[8] = {h0.x,h0.y,h0.z,h0.w,h1.x,h1.y,h1.z,h1.w};
      float vv[8] = {v0.x,v0.y,v0.z,v0.w,v1.x,v1.y,v1.z,v1.w};
      #pragma unroll
      for (int ee = 0; ee < 8; ++ee){
        float a = fmaf(bf2f(e[ee]), C, hw[ee]);
        sacc = fmaf(vv[ee], __builtin_amdgcn_rcpf(1.f + __builtin_amdgcn_exp2f(a)), sacc);
      }
    }
    sacc += __shfl_xor(sacc, 1);
    sacc += __shfl_xor(sacc, 2);
    if (kq == 0) scores[((size_t)t*64 + b)*512 + lc*64 + l] = vsumf + sacc;
  }
}

// ----------------------------- softmax -> aw (bf16) ------------------------
__global__ __launch_bounds__(256) void softmax_aw(
    const float* __restrict__ scores, unsigned short* __restrict__ awb){
  __shared__ float red[4];
  const int row = blockIdx.x, tid = threadIdx.x;
  const int lane = tid & 63, wv = tid >> 6;
  float v0 = scores[(size_t)row*512 + tid];
  float v1 = scores[(size_t)row*512 + tid + 256];
  float mx = fmaxf(v0, v1);
  #pragma unroll
  for (int off=32; off; off>>=1) mx = fmaxf(mx, __shfl_xor(mx, off));
  if (lane == 0) red[wv] = mx;
  __syncthreads();
  mx = fmaxf(fmaxf(red[0],red[1]), fmaxf(red[2],red[3]));
  __syncthreads();
  float e0 = __expf(v0 - mx), e1 = __expf(v1 - mx);
  float ps = e0 + e1;
  #pragma unroll
  for (int off=32; off; off>>=1) ps += __shfl_xor(ps, off);
  if (lane == 0) red[wv] = ps;
  __syncthreads();
  float inv = 1.f / (red[0]+red[1]+red[2]+red[3]);
  awb[(size_t)row*512 + tid]       = f2bf(e0 * inv);
  awb[(size_t)row*512 + tid + 256] = f2bf(e1 * inv);
}

// ----------------------------- ctx weighted sum ----------------------------
__global__ __launch_bounds__(256) void ctx_k(
    const unsigned short* __restrict__ awb,     // [3072][512]
    const unsigned short* __restrict__ encout,  // [64*512][512]
    unsigned short* __restrict__ X){
  __shared__ unsigned short awt[512*12];   // [l][tt]
  const int tid = threadIdx.x;
  const int b = blockIdx.x >> 2, t0 = (blockIdx.x & 3)*12;
  for (int i = tid; i < 12*256; i += 256){
    int tt = i >> 8, d = i & 255;
    unsigned u = *(const unsigned*)&awb[((size_t)(t0+tt)*64 + b)*512 + d*2];
    awt[(2*d)*12 + tt]   = (unsigned short)(u & 0xffffu);
    awt[(2*d+1)*12 + tt] = (unsigned short)(u >> 16);
  }
  __syncthreads();
  float a0[12], a1[12];
  #pragma unroll
  for (int j = 0; j < 12; ++j){ a0[j] = 0.f; a1[j] = 0.f; }
  const unsigned* eo = (const unsigned*)(encout + (size_t)b*512*512) + tid;
  for (int ll = 0; ll < 512; ++ll){
    unsigned ee = eo[(size_t)ll*256];
    float e0 = __uint_as_float((ee & 0xffffu) << 16);
    float e1 = __uint_as_float(ee & 0xffff0000u);
    const unsigned* wp2 = (const unsigned*)&awt[ll*12];
    float w[12];
    #pragma unroll
    for (int z = 0; z < 6; ++z){
      unsigned wu = wp2[z];
      w[2*z]   = bf2f((unsigned short)(wu & 0xffffu));
      w[2*z+1] = bf2f((unsigned short)(wu >> 16));
    }
    #pragma unroll
    for (int j = 0; j < 12; ++j){
      a0[j] = fmaf(w[j], e0, a0[j]);
      a1[j] = fmaf(w[j], e1, a1[j]);
    }
  }
  #pragma unroll
  for (int j = 0; j < 12; ++j){
    size_t r = (size_t)(t0+j)*64 + b;
    unsigned pk = ((unsigned)f2bf(a0[j])) | (((unsigned)f2bf(a1[j])) << 16);
    *(unsigned*)&X[r*1024 + 512 + 2*tid] = pk;
  }
}

// ----------------------------- projection ----------------------------------
__global__ void proj_k(const unsigned short* __restrict__ outs,
                       const float* __restrict__ pw, const float* __restrict__ pb,
                       float* __restrict__ out){
  int gid = blockIdx.x*256 + threadIdx.x;
  if (gid >= 64*48*7) return;
  int r = gid / 7, oc = gid % 7;
  int b = r & 63, t = r >> 6;
  const unsigned short* orow = outs + (size_t)r*512;
  const float* wrow = pw + oc*512;
  float s = pb[oc];
  for (int k = 0; k < 512; k += 8){
    bf16x8 o8 = *(const bf16x8*)&orow[k];
    #pragma unroll
    for (int e=0;e<8;e++) s += bf2f(((unsigned short*)&o8)[e]) * wrow[k+e];
  }
  out[((size_t)b*48 + t)*7 + oc] = s;
}

// ----------------------------- launch --------------------------------------
extern "C" void kernel_launch(void* const* d_in, const int* in_sizes, int n_in,
                              void* d_out, int out_size, void* d_ws, size_t ws_size,
                              hipStream_t stream){
  (void)in_sizes; (void)n_in; (void)out_size; (void)ws_size;
  const float* x_enc   = (const float*)d_in[0];
  const float* x_dec   = (const float*)d_in[1];
  const float* w_emb_e = (const float*)d_in[2];
  const float* w_emb_d = (const float*)d_in[3];
  const float* enc_Wih = (const float*)d_in[4];
  const float* enc_Whh = (const float*)d_in[5];
  const float* enc_b   = (const float*)d_in[6];
  const float* dec_Wih = (const float*)d_in[7];
  const float* dec_Whh = (const float*)d_in[8];
  const float* dec_b   = (const float*)d_in[9];
  const float* attn_W  = (const float*)d_in[10];
  const float* attn_b  = (const float*)d_in[11];
  const float* vvec    = (const float*)d_in[12];
  const float* fc_W    = (const float*)d_in[13];
  const float* fc_b    = (const float*)d_in[14];
  const float* proj_W  = (const float*)d_in[15];
  const float* proj_b  = (const float*)d_in[16];
  float* out = (float*)d_out;

  char* ws = (char*)d_ws;
  size_t off = 0;
  auto alloc = [&](size_t bytes)->char*{
    char* p = ws + off;
    off = (off + bytes + 255) & ~(size_t)255;
    return p;
  };
  unsigned short* encxw  = (unsigned short*)alloc(512ull*64*2048*2); // all steps
  unsigned short* encin  = (unsigned short*)alloc(512ull*64*512*2);  // embed; reused as enc_part
  unsigned short* encout = (unsigned short*)alloc(64ull*512*512*2);
  unsigned short* xs     = (unsigned short*)alloc(64ull*48*512*2);
  unsigned short* xg     = (unsigned short*)alloc(64ull*48*2048*2);
  unsigned short* Xb     = (unsigned short*)alloc(3072ull*1024*2);
  float* hwh    = (float*)alloc(3072ull*512*4);
  float* scores = (float*)alloc(3072ull*512*4);
  unsigned short* awb    = (unsigned short*)alloc(3072ull*512*2);
  unsigned short* outsb  = (unsigned short*)alloc(3072ull*512*2);
  unsigned short* wih_e  = (unsigned short*)alloc(2048ull*512*2);
  unsigned short* whh_e  = (unsigned short*)alloc(2048ull*512*2);
  unsigned short* wih_d  = (unsigned short*)alloc(2048ull*512*2);
  unsigned short* whh_d  = (unsigned short*)alloc(2048ull*512*2);
  unsigned short* whq    = (unsigned short*)alloc(512ull*512*2);
  unsigned short* weq    = (unsigned short*)alloc(512ull*512*2);
  unsigned short* fcw    = (unsigned short*)alloc(512ull*1024*2);
  unsigned long long* hbuf = (unsigned long long*)alloc(2ull*64*128*8);
  float* cbuf   = (float*)alloc(64ull*512*4);
  unsigned* eslots = (unsigned*)alloc(4*64*4);
  unsigned* dslots = (unsigned*)alloc(4*64*4);

  hipMemsetAsync(hbuf, 0, 2ull*64*128*8, stream);
  hipMemsetAsync(cbuf, 0, 64ull*512*4, stream);
  hipMemsetAsync(eslots, 0, 4*64*4, stream);
  hipMemsetAsync(dslots, 0, 4*64*4, stream);

  cast_k<<<4096, 256, 0, stream>>>(enc_Wih, wih_e, 2048*512);
  cast_k<<<4096, 256, 0, stream>>>(enc_Whh, whh_e, 2048*512);
  cast_k<<<4096, 256, 0, stream>>>(dec_Wih, wih_d, 2048*512);
  cast_k<<<4096, 256, 0, stream>>>(dec_Whh, whh_d, 2048*512);
  cast_k<<<2048, 256, 0, stream>>>(fc_W, fcw, 512*1024);
  split_attn_k<<<1024, 256, 0, stream>>>(attn_W, whq, weq);

  embed_k<<<512, 512, 0, stream>>>(x_enc, w_emb_e, encin, 64, 512, 0, 512, 0);
  embed_k<<<64, 512, 0, stream>>>(x_dec, w_emb_d, xs, 64, 144, 48, 48, 1);

  // xg = xs @ dec_Wih^T + dec_b   [3072][2048]
  gemm_nt<<<dim3(16, 24), 256, 0, stream>>>(xs, 512, wih_d, 512, dec_b, xg, 2048, 3072, 2048, 512);

  // ONE staging gemm for all 512 encoder steps: [32768][2048]
  gemm_nt<<<dim3(16, 256), 256, 0, stream>>>(encin, 512, wih_e, 512, enc_b, encxw, 2048, 32768, 2048, 512);
  // ONE persistent lstm launch, 512 steps
  lstm_enc<<<64, 512, 0, stream>>>(encxw, whh_e, cbuf, hbuf, encout, 0, 512, eslots);

  // enc_part = encout @ We^T + attn_b  (reuses encin buffer)
  gemm_nt<<<dim3(4, 256), 256, 0, stream>>>(encout, 512, weq, 512, attn_b, encin, 512, 32768, 512, 512);

  // decoder LSTM h-sequence -> X[:, :512]
  dec_h<<<64, 512, 0, stream>>>(xg, whh_d, cbuf, hbuf, Xb, dslots);

  // hWh = h @ Wh^T  (f32)
  gemm_ntf<<<dim3(4, 24), 256, 0, stream>>>(Xb, 1024, whq, 512, hwh, 512, 3072, 512, 512);

  // scores, softmax, ctx
  attn_scores<<<512, 256, 0, stream>>>(encin /*enc_part*/, hwh, vvec, scores);
  softmax_aw<<<3072, 256, 0, stream>>>(scores, awb);
  ctx_k<<<256, 256, 0, stream>>>(awb, encout, Xb);

  // fc: [h|ctx] @ fc_W^T + fc_b
  gemm_nt<<<dim3(4, 24), 256, 0, stream>>>(Xb, 1024, fcw, 1024, fc_b, outsb, 512, 3072, 512, 1024);

  proj_k<<<84, 256, 0, stream>>>(outsb, proj_W, proj_b, out);
}